// Round 1
// 528.575 us; speedup vs baseline: 1.0284x; 1.0284x over previous
//
#include <hip/hip_runtime.h>
#include <hip/hip_bf16.h>
#include <cstdint>

// ---------------------------------------------------------------------------
// RoutesEncoder: gather+max over graph embedding, then 3x (Linear + ReLU).
// Established: fp32 inputs, fp32 output, bf16-space comparison (thr 1.578e-2),
// idx int32/int64 autodetected. Internals: bf16 MFMA, fp32 accumulation.
// R6: GEMM rewritten as 256x256 / 8-wave / deep-pipeline schedule
//     (T1 XCD swizzle + T2 LDS XOR swizzle + T3/T4 phased counted-vmcnt +
//      T5 setprio). Ring-of-4 K-tile LDS buffers (BK=32, 128 KiB LDS),
//     prefetch distance 3, one vmcnt(8) per K-tile (never 0 in main loop).
//     Race-free: buffer (t+3)&3 was last read in tile t-1, all waves passed
//     the t-1 end barrier before any t+3 load is issued.
// ---------------------------------------------------------------------------

typedef __attribute__((ext_vector_type(8))) short          bf16x8; // MFMA A/B frag
typedef __attribute__((ext_vector_type(8))) unsigned short u16x8;  // 16B vector ld/st
typedef __attribute__((ext_vector_type(4))) float          f32x4;  // MFMA C/D frag

__device__ __forceinline__ unsigned short f2b_rne(float f) {
    union { float f; uint32_t i; } x; x.f = f;
    uint32_t lsb = (x.i >> 16) & 1u;
    return (unsigned short)((x.i + 0x7fffu + lsb) >> 16);
}
__device__ __forceinline__ float b2f(unsigned short u) {
    union { float f; uint32_t i; } x; x.i = ((uint32_t)u) << 16; return x.f;
}

// async 16B global->LDS DMA. HW scatters lane i to ldsbase + i*16; our lptr is
// exactly base + lane*16 in wave-lane order (contract verified round 4).
__device__ __forceinline__ void async_copy16(const void* gptr, void* lptr) {
    __builtin_amdgcn_global_load_lds(
        (const __attribute__((address_space(1))) unsigned int*)gptr,
        (__attribute__((address_space(3))) unsigned int*)lptr, 16, 0, 0);
}

// ---------------------------------------------------------------------------
// Streaming cast: graph fp32 -> bf16 (RNE). 8 floats/thread.
// ---------------------------------------------------------------------------
__global__ __launch_bounds__(256)
void convert_f32_bf16(const float* __restrict__ in, unsigned short* __restrict__ out)
{
    const size_t i = ((size_t)blockIdx.x * 256 + threadIdx.x) * 8;
    const float4* p = reinterpret_cast<const float4*>(in + i);
    float4 v0 = p[0], v1 = p[1];
    u16x8 o;
    o[0] = f2b_rne(v0.x); o[1] = f2b_rne(v0.y); o[2] = f2b_rne(v0.z); o[3] = f2b_rne(v0.w);
    o[4] = f2b_rne(v1.x); o[5] = f2b_rne(v1.y); o[6] = f2b_rne(v1.z); o[7] = f2b_rne(v1.w);
    *reinterpret_cast<u16x8*>(out + i) = o;
}

// ---------------------------------------------------------------------------
// Transpose-cast: W [K,N] fp32 -> Wt [N,K] bf16 (RNE).
// ---------------------------------------------------------------------------
__global__ void transpose_f32_bf16(const float* __restrict__ W,
                                   unsigned short* __restrict__ Wt,
                                   int K, int N)
{
    __shared__ float tile[32][33];
    const int n0 = blockIdx.x * 32;
    const int k0 = blockIdx.y * 32;
    const int tx = threadIdx.x & 31;
    const int ty = threadIdx.x >> 5;
#pragma unroll
    for (int i = 0; i < 32; i += 8)
        tile[ty + i][tx] = W[(size_t)(k0 + ty + i) * N + (n0 + tx)];
    __syncthreads();
#pragma unroll
    for (int i = 0; i < 32; i += 8)
        Wt[(size_t)(n0 + ty + i) * K + (k0 + tx)] = f2b_rne(tile[tx][ty + i]);
}

// ---------------------------------------------------------------------------
// Gather+max from BF16 table: one wave handles FOUR routes (4 independent
// load chains). Row = 1KB = 64 lanes x 16B -> one load per row.
// ---------------------------------------------------------------------------
__global__ void gather_max_bf16(const unsigned short* __restrict__ graphb,
                                const int* __restrict__ idx32,
                                unsigned short* __restrict__ routes)
{
    bool is64 = true;
#pragma unroll
    for (int k = 0; k < 64; k++) is64 &= (idx32[2 * k + 1] == 0);
    const int stride = is64 ? 64 : 32;
    const int step   = is64 ? 2  : 1;

    const int wave  = threadIdx.x >> 6;
    const int lane  = threadIdx.x & 63;
    const int route = (blockIdx.x * 4 + wave) * 4;
    const int col   = lane * 8;                 // 8 bf16 = 16B per lane

    float m[4][8];
#pragma unroll
    for (int t = 0; t < 4; t++)
#pragma unroll
        for (int j = 0; j < 8; j++) m[t][j] = -INFINITY;

    const int* ip = idx32 + (size_t)route * stride;
#pragma unroll 2
    for (int l = 0; l < 32; l++) {
        u16x8 v[4];
#pragma unroll
        for (int t = 0; t < 4; t++) {
            const int node = ip[t * stride + l * step];
            v[t] = *reinterpret_cast<const u16x8*>(graphb + (size_t)node * 512 + col);
        }
#pragma unroll
        for (int t = 0; t < 4; t++)
#pragma unroll
            for (int j = 0; j < 8; j++)
                m[t][j] = fmaxf(m[t][j], b2f(v[t][j]));
    }
#pragma unroll
    for (int t = 0; t < 4; t++) {
        u16x8 o;
#pragma unroll
        for (int j = 0; j < 8; j++) {
            union { float f; uint32_t i; } x; x.f = m[t][j];
            o[j] = (unsigned short)(x.i >> 16);   // exact: max of bf16s is a bf16
        }
        *reinterpret_cast<u16x8*>(routes + (size_t)(route + t) * 512 + col) = o;
    }
}

// fp32-table fallback (round-4 version, 2 routes/wave) if ws can't hold graphb
__global__ void gather_max_f32(const float* __restrict__ graph,
                               const int* __restrict__ idx32,
                               unsigned short* __restrict__ routes)
{
    bool is64 = true;
#pragma unroll
    for (int k = 0; k < 64; k++) is64 &= (idx32[2 * k + 1] == 0);
    const int stride = is64 ? 64 : 32;
    const int step   = is64 ? 2  : 1;

    const int wave  = threadIdx.x >> 6;
    const int lane  = threadIdx.x & 63;
    const int route = (blockIdx.x * 4 + wave) * 2;
    const int col   = lane * 8;

    float m0[8], m1[8];
#pragma unroll
    for (int j = 0; j < 8; j++) { m0[j] = -INFINITY; m1[j] = -INFINITY; }

    const int* ip0 = idx32 + (size_t)route * stride;
    const int* ip1 = ip0 + stride;
#pragma unroll 4
    for (int l = 0; l < 32; l++) {
        const int n0 = ip0[l * step];
        const int n1 = ip1[l * step];
        const float4* p0 = reinterpret_cast<const float4*>(graph + (size_t)n0 * 512 + col);
        const float4* p1 = reinterpret_cast<const float4*>(graph + (size_t)n1 * 512 + col);
        float4 a0 = p0[0], a1 = p0[1];
        float4 b0 = p1[0], b1 = p1[1];
        m0[0] = fmaxf(m0[0], a0.x); m0[1] = fmaxf(m0[1], a0.y);
        m0[2] = fmaxf(m0[2], a0.z); m0[3] = fmaxf(m0[3], a0.w);
        m0[4] = fmaxf(m0[4], a1.x); m0[5] = fmaxf(m0[5], a1.y);
        m0[6] = fmaxf(m0[6], a1.z); m0[7] = fmaxf(m0[7], a1.w);
        m1[0] = fmaxf(m1[0], b0.x); m1[1] = fmaxf(m1[1], b0.y);
        m1[2] = fmaxf(m1[2], b0.z); m1[3] = fmaxf(m1[3], b0.w);
        m1[4] = fmaxf(m1[4], b1.x); m1[5] = fmaxf(m1[5], b1.y);
        m1[6] = fmaxf(m1[6], b1.z); m1[7] = fmaxf(m1[7], b1.w);
    }
    u16x8 o0, o1;
#pragma unroll
    for (int j = 0; j < 8; j++) { o0[j] = f2b_rne(m0[j]); o1[j] = f2b_rne(m1[j]); }
    *reinterpret_cast<u16x8*>(routes + (size_t)route * 512 + col)       = o0;
    *reinterpret_cast<u16x8*>(routes + (size_t)(route + 1) * 512 + col) = o1;
}

// ---------------------------------------------------------------------------
// GEMM (B^T): C = relu(A[M,K]*Bt[N,K]^T + bias). bf16 in, fp32 accum.
// 256x256 tile, 8 waves (2M x 4N), 128x64 per wave, acc[8][4] 16x16x32 MFMA.
// BK=32 K-tiles in a ring of 4 LDS buffers (128 KiB total), prefetch
// distance 3. Per tile: 2 phases x {ds_read frags, issue 2 DMA loads,
// barrier, setprio(1), 16 MFMA, setprio(0), barrier}; one counted
// s_waitcnt vmcnt(8) per tile (drains tile t+1's loads only).
// LDS swizzle: 64B rows, 4 chunks of 16B; chunk c of row r stored at
// position c ^ ((r>>1)&3) -> frag reads spread over all 8 bank-quads
// within each 16-lane phase group (2-way = free).
// Per-thread load ledger (4 loads/tile): prologue issues tiles 0..2 (12),
// vmcnt(8) -> tile0 ready. In tile t issue tile t+3 (4); end-of-tile
// outstanding = {t+1,t+2,t+3} -> vmcnt(8) retires t+1. Tail: vmcnt(4)/(0).
// ---------------------------------------------------------------------------
template <int K, typename OutT>
__global__ __launch_bounds__(512, 2)
void gemm_bt_relu_8p(const unsigned short* __restrict__ A,
                     const unsigned short* __restrict__ Bt,
                     const float* __restrict__ bias,
                     OutT* __restrict__ C)
{
    constexpr int N  = 1024;
    constexpr int BK = 32;
    constexpr int NT = K / BK;

    __shared__ __align__(16) unsigned short As[4][256 * BK];  // 64 KB
    __shared__ __align__(16) unsigned short Bs[4][256 * BK];  // 64 KB

    const int tid  = threadIdx.x;
    const int wave = tid >> 6;
    const int lane = tid & 63;
    const int quad = lane >> 4;
    const int l16  = lane & 15;
    const int wm   = (wave >> 2) * 128;
    const int wn   = (wave & 3) * 64;

    // XCD-aware bijective swizzle: 256 blocks, 8 XCDs, 32 contiguous tiles
    // per XCD (4 bn-neighbors share an A-panel within one XCD's chunk).
    const int swz = (blockIdx.x & 7) * 32 + (blockIdx.x >> 3);
    const int bm  = (swz >> 2) * 256;
    const int bn  = (swz & 3) * 256;

    // staging map: slot s = j*512+tid -> row r = s>>2, stored pos p = s&3,
    // source chunk c = p ^ ((r>>1)&3)  (involution => read uses same XOR).
    const unsigned short* ag[2];
    const unsigned short* bg[2];
    int ao[2];
#pragma unroll
    for (int j = 0; j < 2; j++) {
        const int s = j * 512 + tid;
        const int r = s >> 2;
        const int c = (s & 3) ^ ((r >> 1) & 3);
        ag[j] = A  + (size_t)(bm + r) * K + c * 8;
        bg[j] = Bt + (size_t)(bn + r) * K + c * 8;
        ao[j] = s * 8;                       // element offset inside a buffer
    }

    // prologue: prefetch K-tiles 0..2
#pragma unroll
    for (int t = 0; t < 3; t++) {
#pragma unroll
        for (int j = 0; j < 2; j++) async_copy16(ag[j] + t * BK, &As[t][ao[j]]);
#pragma unroll
        for (int j = 0; j < 2; j++) async_copy16(bg[j] + t * BK, &Bs[t][ao[j]]);
    }
    asm volatile("s_waitcnt vmcnt(8)" ::: "memory");   // tile 0 landed
    __builtin_amdgcn_s_barrier();

    f32x4 acc[8][4] = {};

    for (int t = 0; t < NT; ++t) {
        const unsigned short* Ab = As[t & 3];
        const unsigned short* Bb = Bs[t & 3];

        // ---- phase 0: all B-frags + A-frags mi 0..3; issue A(t+3); 16 MFMA
        bf16x8 bf[4], a0[4];
#pragma unroll
        for (int i = 0; i < 4; i++) {
            const int row = wn + i * 16 + l16;
            bf[i] = *reinterpret_cast<const bf16x8*>(
                Bb + row * BK + ((quad ^ ((row >> 1) & 3)) << 3));
        }
#pragma unroll
        for (int i = 0; i < 4; i++) {
            const int row = wm + i * 16 + l16;
            a0[i] = *reinterpret_cast<const bf16x8*>(
                Ab + row * BK + ((quad ^ ((row >> 1) & 3)) << 3));
        }
        if (t + 3 < NT) {
            const int tb = (t + 3) & 3;
            const int k0 = (t + 3) * BK;
#pragma unroll
            for (int j = 0; j < 2; j++) async_copy16(ag[j] + k0, &As[tb][ao[j]]);
        }
        __builtin_amdgcn_s_barrier();
        __builtin_amdgcn_s_setprio(1);
#pragma unroll
        for (int mi = 0; mi < 4; mi++)
#pragma unroll
            for (int ni = 0; ni < 4; ni++)
                acc[mi][ni] = __builtin_amdgcn_mfma_f32_16x16x32_bf16(
                    a0[mi], bf[ni], acc[mi][ni], 0, 0, 0);
        __builtin_amdgcn_s_setprio(0);
        __builtin_amdgcn_s_barrier();

        // ---- phase 1: A-frags mi 4..7; issue B(t+3); 16 MFMA
        bf16x8 a1[4];
#pragma unroll
        for (int i = 0; i < 4; i++) {
            const int row = wm + 64 + i * 16 + l16;
            a1[i] = *reinterpret_cast<const bf16x8*>(
                Ab + row * BK + ((quad ^ ((row >> 1) & 3)) << 3));
        }
        if (t + 3 < NT) {
            const int tb = (t + 3) & 3;
            const int k0 = (t + 3) * BK;
#pragma unroll
            for (int j = 0; j < 2; j++) async_copy16(bg[j] + k0, &Bs[tb][ao[j]]);
        }
        __builtin_amdgcn_s_barrier();
        __builtin_amdgcn_s_setprio(1);
#pragma unroll
        for (int mi = 0; mi < 4; mi++)
#pragma unroll
            for (int ni = 0; ni < 4; ni++)
                acc[mi + 4][ni] = __builtin_amdgcn_mfma_f32_16x16x32_bf16(
                    a1[mi], bf[ni], acc[mi + 4][ni], 0, 0, 0);
        __builtin_amdgcn_s_setprio(0);
        // counted drain: retire exactly tile t+1's 4 loads, keep the rest
        if (t + 3 < NT)      asm volatile("s_waitcnt vmcnt(8)" ::: "memory");
        else if (t + 2 < NT) asm volatile("s_waitcnt vmcnt(4)" ::: "memory");
        else                 asm volatile("s_waitcnt vmcnt(0)" ::: "memory");
        __builtin_amdgcn_s_barrier();
    }

    // epilogue: bias + relu + store. C/D layout: row = quad*4 + r, col = l16
#pragma unroll
    for (int ni = 0; ni < 4; ni++) {
        const int n  = bn + wn + ni * 16 + l16;
        const float bv = bias[n];
#pragma unroll
        for (int mi = 0; mi < 8; mi++) {
            const int mbase = bm + wm + mi * 16 + quad * 4;
#pragma unroll
            for (int r = 0; r < 4; r++) {
                float v = fmaxf(acc[mi][ni][r] + bv, 0.0f);
                if constexpr (sizeof(OutT) == 2)
                    C[(size_t)(mbase + r) * N + n] = (OutT)f2b_rne(v);
                else
                    C[(size_t)(mbase + r) * N + n] = (OutT)v;
            }
        }
    }
}

// ---------------------------------------------------------------------------
// Launch
// ---------------------------------------------------------------------------
extern "C" void kernel_launch(void* const* d_in, const int* in_sizes, int n_in,
                              void* d_out, int out_size, void* d_ws, size_t ws_size,
                              hipStream_t stream)
{
    constexpr int N_ROUTES = 16384;
    constexpr int N_NODES  = 100000;
    constexpr int D_GRAPH  = 512;
    constexpr int D_ROUTE  = 1024;

    const float* graph = (const float*)d_in[0];
    const int*   idx   = (const int*)d_in[1];
    const float* W0    = (const float*)d_in[2];
    const float* b0    = (const float*)d_in[3];
    const float* W1    = (const float*)d_in[4];
    const float* b1    = (const float*)d_in[5];
    const float* W2    = (const float*)d_in[6];
    const float* b2    = (const float*)d_in[7];
    float*       out   = (float*)d_out;

    // workspace carve
    char* w = (char*)d_ws;
    unsigned short* Wt0    = (unsigned short*)w; w += (size_t)D_ROUTE * D_GRAPH * 2;  // 1 MB
    unsigned short* Wt1    = (unsigned short*)w; w += (size_t)D_ROUTE * D_ROUTE * 2;  // 2 MB
    unsigned short* Wt2    = (unsigned short*)w; w += (size_t)D_ROUTE * D_ROUTE * 2;  // 2 MB
    unsigned short* routes = (unsigned short*)w; w += (size_t)N_ROUTES * D_GRAPH * 2; // 16 MB
    unsigned short* x1     = (unsigned short*)w; w += (size_t)N_ROUTES * D_ROUTE * 2; // 32 MB
    unsigned short* x2     = (unsigned short*)w; w += (size_t)N_ROUTES * D_ROUTE * 2; // 32 MB
    unsigned short* graphb = (unsigned short*)w;
    const size_t need_bf16 = (size_t)(w - (char*)d_ws) + (size_t)N_NODES * D_GRAPH * 2;
    const bool   use_bf16  = (ws_size >= need_bf16);

    // 1) weight transpose-casts (fp32 [K,N] -> bf16 [N,K])
    transpose_f32_bf16<<<dim3(D_ROUTE / 32, D_GRAPH / 32), 256, 0, stream>>>(W0, Wt0, D_GRAPH, D_ROUTE);
    transpose_f32_bf16<<<dim3(D_ROUTE / 32, D_ROUTE / 32), 256, 0, stream>>>(W1, Wt1, D_ROUTE, D_ROUTE);
    transpose_f32_bf16<<<dim3(D_ROUTE / 32, D_ROUTE / 32), 256, 0, stream>>>(W2, Wt2, D_ROUTE, D_ROUTE);

    // 2) gather + max
    if (use_bf16) {
        convert_f32_bf16<<<(N_NODES * D_GRAPH / 8) / 256, 256, 0, stream>>>(graph, graphb);
        gather_max_bf16<<<N_ROUTES / 16, 256, 0, stream>>>(graphb, idx, routes);
    } else {
        gather_max_f32<<<N_ROUTES / 8, 256, 0, stream>>>(graph, idx, routes);
    }

    // 3) linear chain: 256x256-tile pipelined GEMMs (grid = 64x4 = 256 = #CUs)
    gemm_bt_relu_8p<512,  unsigned short><<<256, 512, 0, stream>>>(routes, Wt0, b0, x1);
    gemm_bt_relu_8p<1024, unsigned short><<<256, 512, 0, stream>>>(x1, Wt1, b1, x2);
    gemm_bt_relu_8p<1024, float><<<256, 512, 0, stream>>>(x2, Wt2, b2, out);
}

// Round 2
// 512.958 us; speedup vs baseline: 1.0597x; 1.0304x over previous
//
#include <hip/hip_runtime.h>
#include <hip/hip_bf16.h>
#include <cstdint>

// ---------------------------------------------------------------------------
// RoutesEncoder: gather+max over graph embedding, then 3x (Linear + ReLU).
// Established: fp32 inputs, fp32 output, bf16-space comparison (thr 1.578e-2),
// idx int32/int64 autodetected. Internals: bf16 MFMA, fp32 accumulation.
// R6: GEMM = 256x256 / 8-wave / ring-4 BK=32 deep pipeline (T1+T2+T3/T4+T5),
//     counted vmcnt(8), never 0 in main loop.  (kept unchanged this round)
// R7: (a) gather: route indices staged in LDS (removes global idx load from
//         the dependent addr->load chain) + unroll 4 => 16 row-loads in
//         flight per wave (was ~8 with global idx on the chain);
//     (b) convert + 3 weight transposes merged into ONE prep kernel
//         (grid-partitioned) => 5 launches total (was 8).
// ---------------------------------------------------------------------------

typedef __attribute__((ext_vector_type(8))) short          bf16x8; // MFMA A/B frag
typedef __attribute__((ext_vector_type(8))) unsigned short u16x8;  // 16B vector ld/st
typedef __attribute__((ext_vector_type(4))) float          f32x4;  // MFMA C/D frag

__device__ __forceinline__ unsigned short f2b_rne(float f) {
    union { float f; uint32_t i; } x; x.f = f;
    uint32_t lsb = (x.i >> 16) & 1u;
    return (unsigned short)((x.i + 0x7fffu + lsb) >> 16);
}
__device__ __forceinline__ float b2f(unsigned short u) {
    union { float f; uint32_t i; } x; x.i = ((uint32_t)u) << 16; return x.f;
}

// async 16B global->LDS DMA. HW scatters lane i to ldsbase + i*16; our lptr is
// exactly base + lane*16 in wave-lane order (contract verified round 4).
__device__ __forceinline__ void async_copy16(const void* gptr, void* lptr) {
    __builtin_amdgcn_global_load_lds(
        (const __attribute__((address_space(1))) unsigned int*)gptr,
        (__attribute__((address_space(3))) unsigned int*)lptr, 16, 0, 0);
}

// ---------------------------------------------------------------------------
// Prep kernel: [blocks 0..conv_blocks) stream-cast graph fp32->bf16 (RNE);
// remaining 2560 blocks transpose-cast the three weight matrices
// (fp32 [K,1024] -> bf16 [1024,K]).  One kernel = fewer dependent launches.
// ---------------------------------------------------------------------------
__global__ __launch_bounds__(256)
void prep(int conv_blocks,
          const float* __restrict__ graph, unsigned short* __restrict__ graphb,
          const float* __restrict__ W0, unsigned short* __restrict__ Wt0,
          const float* __restrict__ W1, unsigned short* __restrict__ Wt1,
          const float* __restrict__ W2, unsigned short* __restrict__ Wt2)
{
    __shared__ float tile[32][33];

    if ((int)blockIdx.x < conv_blocks) {
        // ---- streaming cast: 8 floats/thread
        const size_t i = ((size_t)blockIdx.x * 256 + threadIdx.x) * 8;
        const float4* p = reinterpret_cast<const float4*>(graph + i);
        float4 v0 = p[0], v1 = p[1];
        u16x8 o;
        o[0] = f2b_rne(v0.x); o[1] = f2b_rne(v0.y); o[2] = f2b_rne(v0.z); o[3] = f2b_rne(v0.w);
        o[4] = f2b_rne(v1.x); o[5] = f2b_rne(v1.y); o[6] = f2b_rne(v1.z); o[7] = f2b_rne(v1.w);
        *reinterpret_cast<u16x8*>(graphb + i) = o;
        return;
    }

    // ---- transpose-cast region: W0 (K=512): 512 blocks; W1,W2 (K=1024): 1024 each
    int b = blockIdx.x - conv_blocks;
    const float* W; unsigned short* Wt; int K;
    if (b < 512)       { W = W0; Wt = Wt0; K = 512;  }
    else if (b < 1536) { b -= 512;  W = W1; Wt = Wt1; K = 1024; }
    else               { b -= 1536; W = W2; Wt = Wt2; K = 1024; }
    constexpr int N = 1024;
    const int n0 = (b & 31) * 32;        // N/32 = 32 tiles across
    const int k0 = (b >> 5) * 32;
    const int tx = threadIdx.x & 31;
    const int ty = threadIdx.x >> 5;
#pragma unroll
    for (int i = 0; i < 32; i += 8)
        tile[ty + i][tx] = W[(size_t)(k0 + ty + i) * N + (n0 + tx)];
    __syncthreads();
#pragma unroll
    for (int i = 0; i < 32; i += 8)
        Wt[(size_t)(n0 + ty + i) * K + (k0 + tx)] = f2b_rne(tile[tx][ty + i]);
}

// ---------------------------------------------------------------------------
// Gather+max from BF16 table: one wave handles FOUR routes. Row = 1KB =
// 64 lanes x 16B -> one load per row. R7: block's 16x32 indices staged in
// LDS first (coalesced), inner loop reads them via broadcast ds_read =>
// the global idx load leaves the dependent chain; unroll 4 => 16
// independent row-loads in flight per wave.
// ---------------------------------------------------------------------------
__global__ __launch_bounds__(256)
void gather_max_bf16(const unsigned short* __restrict__ graphb,
                     const int* __restrict__ idx32,
                     unsigned short* __restrict__ routes)
{
    __shared__ int sidx[16][32];

    bool is64 = true;
#pragma unroll
    for (int k = 0; k < 64; k++) is64 &= (idx32[2 * k + 1] == 0);
    const int stride = is64 ? 64 : 32;
    const int step   = is64 ? 2  : 1;

    const int route0 = blockIdx.x * 16;
    // cooperative idx stage: 512 entries, 2 per thread
    for (int e = threadIdx.x; e < 512; e += 256) {
        const int r = e >> 5, l = e & 31;
        sidx[r][l] = idx32[(size_t)(route0 + r) * stride + l * step];
    }
    __syncthreads();

    const int wave = threadIdx.x >> 6;
    const int lane = threadIdx.x & 63;
    const int rl   = wave * 4;                  // local route base
    const int col  = lane * 8;                  // 8 bf16 = 16B per lane

    float m[4][8];
#pragma unroll
    for (int t = 0; t < 4; t++)
#pragma unroll
        for (int j = 0; j < 8; j++) m[t][j] = -INFINITY;

#pragma unroll 4
    for (int l = 0; l < 32; l++) {
        u16x8 v[4];
#pragma unroll
        for (int t = 0; t < 4; t++) {
            const int node = sidx[rl + t][l];   // LDS broadcast, ~short latency
            v[t] = *reinterpret_cast<const u16x8*>(graphb + (size_t)node * 512 + col);
        }
#pragma unroll
        for (int t = 0; t < 4; t++)
#pragma unroll
            for (int j = 0; j < 8; j++)
                m[t][j] = fmaxf(m[t][j], b2f(v[t][j]));
    }
#pragma unroll
    for (int t = 0; t < 4; t++) {
        u16x8 o;
#pragma unroll
        for (int j = 0; j < 8; j++) {
            union { float f; uint32_t i; } x; x.f = m[t][j];
            o[j] = (unsigned short)(x.i >> 16);   // exact: max of bf16s is a bf16
        }
        *reinterpret_cast<u16x8*>(routes + (size_t)(route0 + rl + t) * 512 + col) = o;
    }
}

// fp32-table fallback (2 routes/wave) if ws can't hold graphb
__global__ void gather_max_f32(const float* __restrict__ graph,
                               const int* __restrict__ idx32,
                               unsigned short* __restrict__ routes)
{
    bool is64 = true;
#pragma unroll
    for (int k = 0; k < 64; k++) is64 &= (idx32[2 * k + 1] == 0);
    const int stride = is64 ? 64 : 32;
    const int step   = is64 ? 2  : 1;

    const int wave  = threadIdx.x >> 6;
    const int lane  = threadIdx.x & 63;
    const int route = (blockIdx.x * 4 + wave) * 2;
    const int col   = lane * 8;

    float m0[8], m1[8];
#pragma unroll
    for (int j = 0; j < 8; j++) { m0[j] = -INFINITY; m1[j] = -INFINITY; }

    const int* ip0 = idx32 + (size_t)route * stride;
    const int* ip1 = ip0 + stride;
#pragma unroll 4
    for (int l = 0; l < 32; l++) {
        const int n0 = ip0[l * step];
        const int n1 = ip1[l * step];
        const float4* p0 = reinterpret_cast<const float4*>(graph + (size_t)n0 * 512 + col);
        const float4* p1 = reinterpret_cast<const float4*>(graph + (size_t)n1 * 512 + col);
        float4 a0 = p0[0], a1 = p0[1];
        float4 b0 = p1[0], b1 = p1[1];
        m0[0] = fmaxf(m0[0], a0.x); m0[1] = fmaxf(m0[1], a0.y);
        m0[2] = fmaxf(m0[2], a0.z); m0[3] = fmaxf(m0[3], a0.w);
        m0[4] = fmaxf(m0[4], a1.x); m0[5] = fmaxf(m0[5], a1.y);
        m0[6] = fmaxf(m0[6], a1.z); m0[7] = fmaxf(m0[7], a1.w);
        m1[0] = fmaxf(m1[0], b0.x); m1[1] = fmaxf(m1[1], b0.y);
        m1[2] = fmaxf(m1[2], b0.z); m1[3] = fmaxf(m1[3], b0.w);
        m1[4] = fmaxf(m1[4], b1.x); m1[5] = fmaxf(m1[5], b1.y);
        m1[6] = fmaxf(m1[6], b1.z); m1[7] = fmaxf(m1[7], b1.w);
    }
    u16x8 o0, o1;
#pragma unroll
    for (int j = 0; j < 8; j++) { o0[j] = f2b_rne(m0[j]); o1[j] = f2b_rne(m1[j]); }
    *reinterpret_cast<u16x8*>(routes + (size_t)route * 512 + col)       = o0;
    *reinterpret_cast<u16x8*>(routes + (size_t)(route + 1) * 512 + col) = o1;
}

// ---------------------------------------------------------------------------
// GEMM (B^T): C = relu(A[M,K]*Bt[N,K]^T + bias). bf16 in, fp32 accum.
// 256x256 tile, 8 waves (2M x 4N), 128x64 per wave, acc[8][4] 16x16x32 MFMA.
// BK=32 K-tiles in a ring of 4 LDS buffers (128 KiB total), prefetch
// distance 3. Per tile: 2 phases x {ds_read frags, issue 2 DMA loads,
// barrier, setprio(1), 16 MFMA, setprio(0), barrier}; one counted
// s_waitcnt vmcnt(8) per tile (drains tile t+1's loads only).
// LDS swizzle: 64B rows, 4 chunks of 16B; chunk c of row r stored at
// position c ^ ((r>>1)&3) -> frag reads spread over all 8 bank-quads
// within each 16-lane phase group (2-way = free).
// Per-thread load ledger (4 loads/tile): prologue issues tiles 0..2 (12),
// vmcnt(8) -> tile0 ready. In tile t issue tile t+3 (4); end-of-tile
// outstanding = {t+1,t+2,t+3} -> vmcnt(8) retires t+1. Tail: vmcnt(4)/(0).
// ---------------------------------------------------------------------------
template <int K, typename OutT>
__global__ __launch_bounds__(512, 2)
void gemm_bt_relu_8p(const unsigned short* __restrict__ A,
                     const unsigned short* __restrict__ Bt,
                     const float* __restrict__ bias,
                     OutT* __restrict__ C)
{
    constexpr int N  = 1024;
    constexpr int BK = 32;
    constexpr int NT = K / BK;

    __shared__ __align__(16) unsigned short As[4][256 * BK];  // 64 KB
    __shared__ __align__(16) unsigned short Bs[4][256 * BK];  // 64 KB

    const int tid  = threadIdx.x;
    const int wave = tid >> 6;
    const int lane = tid & 63;
    const int quad = lane >> 4;
    const int l16  = lane & 15;
    const int wm   = (wave >> 2) * 128;
    const int wn   = (wave & 3) * 64;

    // XCD-aware bijective swizzle: 256 blocks, 8 XCDs, 32 contiguous tiles
    // per XCD (4 bn-neighbors share an A-panel within one XCD's chunk).
    const int swz = (blockIdx.x & 7) * 32 + (blockIdx.x >> 3);
    const int bm  = (swz >> 2) * 256;
    const int bn  = (swz & 3) * 256;

    // staging map: slot s = j*512+tid -> row r = s>>2, stored pos p = s&3,
    // source chunk c = p ^ ((r>>1)&3)  (involution => read uses same XOR).
    const unsigned short* ag[2];
    const unsigned short* bg[2];
    int ao[2];
#pragma unroll
    for (int j = 0; j < 2; j++) {
        const int s = j * 512 + tid;
        const int r = s >> 2;
        const int c = (s & 3) ^ ((r >> 1) & 3);
        ag[j] = A  + (size_t)(bm + r) * K + c * 8;
        bg[j] = Bt + (size_t)(bn + r) * K + c * 8;
        ao[j] = s * 8;                       // element offset inside a buffer
    }

    // prologue: prefetch K-tiles 0..2
#pragma unroll
    for (int t = 0; t < 3; t++) {
#pragma unroll
        for (int j = 0; j < 2; j++) async_copy16(ag[j] + t * BK, &As[t][ao[j]]);
#pragma unroll
        for (int j = 0; j < 2; j++) async_copy16(bg[j] + t * BK, &Bs[t][ao[j]]);
    }
    asm volatile("s_waitcnt vmcnt(8)" ::: "memory");   // tile 0 landed
    __builtin_amdgcn_s_barrier();

    f32x4 acc[8][4] = {};

    for (int t = 0; t < NT; ++t) {
        const unsigned short* Ab = As[t & 3];
        const unsigned short* Bb = Bs[t & 3];

        // ---- phase 0: all B-frags + A-frags mi 0..3; issue A(t+3); 16 MFMA
        bf16x8 bf[4], a0[4];
#pragma unroll
        for (int i = 0; i < 4; i++) {
            const int row = wn + i * 16 + l16;
            bf[i] = *reinterpret_cast<const bf16x8*>(
                Bb + row * BK + ((quad ^ ((row >> 1) & 3)) << 3));
        }
#pragma unroll
        for (int i = 0; i < 4; i++) {
            const int row = wm + i * 16 + l16;
            a0[i] = *reinterpret_cast<const bf16x8*>(
                Ab + row * BK + ((quad ^ ((row >> 1) & 3)) << 3));
        }
        if (t + 3 < NT) {
            const int tb = (t + 3) & 3;
            const int k0 = (t + 3) * BK;
#pragma unroll
            for (int j = 0; j < 2; j++) async_copy16(ag[j] + k0, &As[tb][ao[j]]);
        }
        __builtin_amdgcn_s_barrier();
        __builtin_amdgcn_s_setprio(1);
#pragma unroll
        for (int mi = 0; mi < 4; mi++)
#pragma unroll
            for (int ni = 0; ni < 4; ni++)
                acc[mi][ni] = __builtin_amdgcn_mfma_f32_16x16x32_bf16(
                    a0[mi], bf[ni], acc[mi][ni], 0, 0, 0);
        __builtin_amdgcn_s_setprio(0);
        __builtin_amdgcn_s_barrier();

        // ---- phase 1: A-frags mi 4..7; issue B(t+3); 16 MFMA
        bf16x8 a1[4];
#pragma unroll
        for (int i = 0; i < 4; i++) {
            const int row = wm + 64 + i * 16 + l16;
            a1[i] = *reinterpret_cast<const bf16x8*>(
                Ab + row * BK + ((quad ^ ((row >> 1) & 3)) << 3));
        }
        if (t + 3 < NT) {
            const int tb = (t + 3) & 3;
            const int k0 = (t + 3) * BK;
#pragma unroll
            for (int j = 0; j < 2; j++) async_copy16(bg[j] + k0, &Bs[tb][ao[j]]);
        }
        __builtin_amdgcn_s_barrier();
        __builtin_amdgcn_s_setprio(1);
#pragma unroll
        for (int mi = 0; mi < 4; mi++)
#pragma unroll
            for (int ni = 0; ni < 4; ni++)
                acc[mi + 4][ni] = __builtin_amdgcn_mfma_f32_16x16x32_bf16(
                    a1[mi], bf[ni], acc[mi + 4][ni], 0, 0, 0);
        __builtin_amdgcn_s_setprio(0);
        // counted drain: retire exactly tile t+1's 4 loads, keep the rest
        if (t + 3 < NT)      asm volatile("s_waitcnt vmcnt(8)" ::: "memory");
        else if (t + 2 < NT) asm volatile("s_waitcnt vmcnt(4)" ::: "memory");
        else                 asm volatile("s_waitcnt vmcnt(0)" ::: "memory");
        __builtin_amdgcn_s_barrier();
    }

    // epilogue: bias + relu + store. C/D layout: row = quad*4 + r, col = l16
#pragma unroll
    for (int ni = 0; ni < 4; ni++) {
        const int n  = bn + wn + ni * 16 + l16;
        const float bv = bias[n];
#pragma unroll
        for (int mi = 0; mi < 8; mi++) {
            const int mbase = bm + wm + mi * 16 + quad * 4;
#pragma unroll
            for (int r = 0; r < 4; r++) {
                float v = fmaxf(acc[mi][ni][r] + bv, 0.0f);
                if constexpr (sizeof(OutT) == 2)
                    C[(size_t)(mbase + r) * N + n] = (OutT)f2b_rne(v);
                else
                    C[(size_t)(mbase + r) * N + n] = (OutT)v;
            }
        }
    }
}

// ---------------------------------------------------------------------------
// Launch
// ---------------------------------------------------------------------------
extern "C" void kernel_launch(void* const* d_in, const int* in_sizes, int n_in,
                              void* d_out, int out_size, void* d_ws, size_t ws_size,
                              hipStream_t stream)
{
    constexpr int N_ROUTES = 16384;
    constexpr int N_NODES  = 100000;
    constexpr int D_GRAPH  = 512;
    constexpr int D_ROUTE  = 1024;

    const float* graph = (const float*)d_in[0];
    const int*   idx   = (const int*)d_in[1];
    const float* W0    = (const float*)d_in[2];
    const float* b0    = (const float*)d_in[3];
    const float* W1    = (const float*)d_in[4];
    const float* b1    = (const float*)d_in[5];
    const float* W2    = (const float*)d_in[6];
    const float* b2    = (const float*)d_in[7];
    float*       out   = (float*)d_out;

    // workspace carve
    char* w = (char*)d_ws;
    unsigned short* Wt0    = (unsigned short*)w; w += (size_t)D_ROUTE * D_GRAPH * 2;  // 1 MB
    unsigned short* Wt1    = (unsigned short*)w; w += (size_t)D_ROUTE * D_ROUTE * 2;  // 2 MB
    unsigned short* Wt2    = (unsigned short*)w; w += (size_t)D_ROUTE * D_ROUTE * 2;  // 2 MB
    unsigned short* routes = (unsigned short*)w; w += (size_t)N_ROUTES * D_GRAPH * 2; // 16 MB
    unsigned short* x1     = (unsigned short*)w; w += (size_t)N_ROUTES * D_ROUTE * 2; // 32 MB
    unsigned short* x2     = (unsigned short*)w; w += (size_t)N_ROUTES * D_ROUTE * 2; // 32 MB
    unsigned short* graphb = (unsigned short*)w;
    const size_t need_bf16 = (size_t)(w - (char*)d_ws) + (size_t)N_NODES * D_GRAPH * 2;
    const bool   use_bf16  = (ws_size >= need_bf16);

    constexpr int CONV_BLOCKS = (N_NODES * D_GRAPH / 8) / 256;   // 25000
    constexpr int TR_BLOCKS   = 512 + 1024 + 1024;               // 2560

    // 1) prep: graph cast (if bf16 path) + 3 weight transpose-casts, one kernel
    const int conv_blocks = use_bf16 ? CONV_BLOCKS : 0;
    prep<<<conv_blocks + TR_BLOCKS, 256, 0, stream>>>(
        conv_blocks, graph, graphb, W0, Wt0, W1, Wt1, W2, Wt2);

    // 2) gather + max
    if (use_bf16) {
        gather_max_bf16<<<N_ROUTES / 16, 256, 0, stream>>>(graphb, idx, routes);
    } else {
        gather_max_f32<<<N_ROUTES / 8, 256, 0, stream>>>(graph, idx, routes);
    }

    // 3) linear chain: 256x256-tile pipelined GEMMs (grid = 64x4 = 256 = #CUs)
    gemm_bt_relu_8p<512,  unsigned short><<<256, 512, 0, stream>>>(routes, Wt0, b0, x1);
    gemm_bt_relu_8p<1024, unsigned short><<<256, 512, 0, stream>>>(x1, Wt1, b1, x2);
    gemm_bt_relu_8p<1024, float><<<256, 512, 0, stream>>>(x2, Wt2, b2, out);
}

// Round 3
// 498.916 us; speedup vs baseline: 1.0895x; 1.0281x over previous
//
#include <hip/hip_runtime.h>
#include <hip/hip_bf16.h>
#include <cstdint>

// ---------------------------------------------------------------------------
// RoutesEncoder: gather+max over graph embedding, then 3x (Linear + ReLU).
// Established: fp32 inputs, fp32 output, bf16-space comparison (thr 1.578e-2),
// idx int32/int64 from in_sizes (host-side). Internals: bf16 MFMA, fp32 accum.
// R6: GEMM = 256x256 / 8-wave / ring-4 BK=32 deep pipeline, counted vmcnt.
// R7: gather idx staged in LDS; prep = convert + transposes merged.
// R8: (a) GEMM: ONE barrier per K-tile (was 4). The post-vmcnt barrier alone
//         publishes tile t+1's DMA writes AND protects ring-buffer reuse;
//         pre-MFMA barriers removed, phases merged (12 ds_read + 4 stage +
//         32 MFMA + vmcnt + barrier per tile).
//     (b) weight transposes moved from prep into the gather launch (hide
//         under gather's latency-bound execution; only GEMM1 needs them).
//     (c) is64 idx-dtype detection moved to host via in_sizes[1] (removes
//         64-global-load preamble from every gather block).
// ---------------------------------------------------------------------------

typedef __attribute__((ext_vector_type(8))) short          bf16x8; // MFMA A/B frag
typedef __attribute__((ext_vector_type(8))) unsigned short u16x8;  // 16B vector ld/st
typedef __attribute__((ext_vector_type(4))) float          f32x4;  // MFMA C/D frag

__device__ __forceinline__ unsigned short f2b_rne(float f) {
    union { float f; uint32_t i; } x; x.f = f;
    uint32_t lsb = (x.i >> 16) & 1u;
    return (unsigned short)((x.i + 0x7fffu + lsb) >> 16);
}
__device__ __forceinline__ float b2f(unsigned short u) {
    union { float f; uint32_t i; } x; x.i = ((uint32_t)u) << 16; return x.f;
}

// async 16B global->LDS DMA. HW scatters lane i to ldsbase + i*16; our lptr is
// exactly base + lane*16 in wave-lane order (contract verified round 4).
__device__ __forceinline__ void async_copy16(const void* gptr, void* lptr) {
    __builtin_amdgcn_global_load_lds(
        (const __attribute__((address_space(1))) unsigned int*)gptr,
        (__attribute__((address_space(3))) unsigned int*)lptr, 16, 0, 0);
}

// ---------------------------------------------------------------------------
// Streaming cast: graph fp32 -> bf16 (RNE). 8 floats/thread. Exact for the
// downstream max since RNE is monotone => max(rne(x)) == rne(max(x)).
// ---------------------------------------------------------------------------
__global__ __launch_bounds__(256)
void convert_f32_bf16(const float* __restrict__ in, unsigned short* __restrict__ out)
{
    const size_t i = ((size_t)blockIdx.x * 256 + threadIdx.x) * 8;
    const float4* p = reinterpret_cast<const float4*>(in + i);
    float4 v0 = p[0], v1 = p[1];
    u16x8 o;
    o[0] = f2b_rne(v0.x); o[1] = f2b_rne(v0.y); o[2] = f2b_rne(v0.z); o[3] = f2b_rne(v0.w);
    o[4] = f2b_rne(v1.x); o[5] = f2b_rne(v1.y); o[6] = f2b_rne(v1.z); o[7] = f2b_rne(v1.w);
    *reinterpret_cast<u16x8*>(out + i) = o;
}

// ---------------------------------------------------------------------------
// Gather+max (blocks [0, gather_blocks)) + weight transpose-casts (rest).
// Gather: one wave = 4 routes, row = 1KB = 64 lanes x 16B; block's 16x32
// indices staged in LDS first so the idx load leaves the dependent chain;
// unroll 4 => 16 independent row-loads in flight per wave.
// Transpose: fp32 W[K,1024] -> bf16 Wt[1024,K], 32x32 tiles; rides in the
// same launch to hide under the gather's latency-bound execution.
// ---------------------------------------------------------------------------
__global__ __launch_bounds__(256)
void gather_tr(int gather_blocks, int stride, int step,
               const unsigned short* __restrict__ graphb,
               const int* __restrict__ idx32,
               unsigned short* __restrict__ routes,
               const float* __restrict__ W0, unsigned short* __restrict__ Wt0,
               const float* __restrict__ W1, unsigned short* __restrict__ Wt1,
               const float* __restrict__ W2, unsigned short* __restrict__ Wt2)
{
    __shared__ int   sidx[16][32];
    __shared__ float tile[32][33];

    if ((int)blockIdx.x < gather_blocks) {
        const int route0 = blockIdx.x * 16;
        // cooperative idx stage: 512 entries, 2 per thread
        for (int e = threadIdx.x; e < 512; e += 256) {
            const int r = e >> 5, l = e & 31;
            sidx[r][l] = idx32[(size_t)(route0 + r) * stride + l * step];
        }
        __syncthreads();

        const int wave = threadIdx.x >> 6;
        const int lane = threadIdx.x & 63;
        const int rl   = wave * 4;                  // local route base
        const int col  = lane * 8;                  // 8 bf16 = 16B per lane

        float m[4][8];
#pragma unroll
        for (int t = 0; t < 4; t++)
#pragma unroll
            for (int j = 0; j < 8; j++) m[t][j] = -INFINITY;

#pragma unroll 4
        for (int l = 0; l < 32; l++) {
            u16x8 v[4];
#pragma unroll
            for (int t = 0; t < 4; t++) {
                const int node = sidx[rl + t][l];   // LDS broadcast
                v[t] = *reinterpret_cast<const u16x8*>(graphb + (size_t)node * 512 + col);
            }
#pragma unroll
            for (int t = 0; t < 4; t++)
#pragma unroll
                for (int j = 0; j < 8; j++)
                    m[t][j] = fmaxf(m[t][j], b2f(v[t][j]));
        }
#pragma unroll
        for (int t = 0; t < 4; t++) {
            u16x8 o;
#pragma unroll
            for (int j = 0; j < 8; j++) {
                union { float f; uint32_t i; } x; x.f = m[t][j];
                o[j] = (unsigned short)(x.i >> 16);   // exact: max of bf16s is a bf16
            }
            *reinterpret_cast<u16x8*>(routes + (size_t)(route0 + rl + t) * 512 + col) = o;
        }
        return;
    }

    // ---- transpose-cast region: W0 (K=512): 512 blocks; W1,W2: 1024 each
    int b = blockIdx.x - gather_blocks;
    const float* W; unsigned short* Wt; int K;
    if (b < 512)       { W = W0; Wt = Wt0; K = 512;  }
    else if (b < 1536) { b -= 512;  W = W1; Wt = Wt1; K = 1024; }
    else               { b -= 1536; W = W2; Wt = Wt2; K = 1024; }
    constexpr int N = 1024;
    const int n0 = (b & 31) * 32;        // N/32 = 32 tiles across
    const int k0 = (b >> 5) * 32;
    const int tx = threadIdx.x & 31;
    const int ty = threadIdx.x >> 5;
#pragma unroll
    for (int i = 0; i < 32; i += 8)
        tile[ty + i][tx] = W[(size_t)(k0 + ty + i) * N + (n0 + tx)];
    __syncthreads();
#pragma unroll
    for (int i = 0; i < 32; i += 8)
        Wt[(size_t)(n0 + ty + i) * K + (k0 + tx)] = f2b_rne(tile[tx][ty + i]);
}

// fp32-table fallback (2 routes/wave) if ws can't hold graphb
__global__ void gather_max_f32(int stride, int step,
                               const float* __restrict__ graph,
                               const int* __restrict__ idx32,
                               unsigned short* __restrict__ routes)
{
    const int wave  = threadIdx.x >> 6;
    const int lane  = threadIdx.x & 63;
    const int route = (blockIdx.x * 4 + wave) * 2;
    const int col   = lane * 8;

    float m0[8], m1[8];
#pragma unroll
    for (int j = 0; j < 8; j++) { m0[j] = -INFINITY; m1[j] = -INFINITY; }

    const int* ip0 = idx32 + (size_t)route * stride;
    const int* ip1 = ip0 + stride;
#pragma unroll 4
    for (int l = 0; l < 32; l++) {
        const int n0 = ip0[l * step];
        const int n1 = ip1[l * step];
        const float4* p0 = reinterpret_cast<const float4*>(graph + (size_t)n0 * 512 + col);
        const float4* p1 = reinterpret_cast<const float4*>(graph + (size_t)n1 * 512 + col);
        float4 a0 = p0[0], a1 = p0[1];
        float4 b0 = p1[0], b1 = p1[1];
        m0[0] = fmaxf(m0[0], a0.x); m0[1] = fmaxf(m0[1], a0.y);
        m0[2] = fmaxf(m0[2], a0.z); m0[3] = fmaxf(m0[3], a0.w);
        m0[4] = fmaxf(m0[4], a1.x); m0[5] = fmaxf(m0[5], a1.y);
        m0[6] = fmaxf(m0[6], a1.z); m0[7] = fmaxf(m0[7], a1.w);
        m1[0] = fmaxf(m1[0], b0.x); m1[1] = fmaxf(m1[1], b0.y);
        m1[2] = fmaxf(m1[2], b0.z); m1[3] = fmaxf(m1[3], b0.w);
        m1[4] = fmaxf(m1[4], b1.x); m1[5] = fmaxf(m1[5], b1.y);
        m1[6] = fmaxf(m1[6], b1.z); m1[7] = fmaxf(m1[7], b1.w);
    }
    u16x8 o0, o1;
#pragma unroll
    for (int j = 0; j < 8; j++) { o0[j] = f2b_rne(m0[j]); o1[j] = f2b_rne(m1[j]); }
    *reinterpret_cast<u16x8*>(routes + (size_t)route * 512 + col)       = o0;
    *reinterpret_cast<u16x8*>(routes + (size_t)(route + 1) * 512 + col) = o1;
}

// ---------------------------------------------------------------------------
// GEMM (B^T): C = relu(A[M,K]*Bt[N,K]^T + bias). bf16 in, fp32 accum.
// 256x256 tile, 8 waves (2M x 4N), 128x64 per wave, acc[8][4] 16x16x32 MFMA.
// BK=32 K-tiles in a ring of 4 LDS buffers (128 KiB), prefetch distance 3.
// R8: ONE barrier per tile. Per tile t:
//   12 ds_read_b128 (A 8 + B 4, from buf[t&3])
//   issue 4 global_load_lds for tile t+3 into buf[(t+3)&3]
//   setprio(1); 32 MFMA; setprio(0)
//   counted s_waitcnt vmcnt(8)  (retires exactly tile t+1's 4 loads)
//   s_barrier                   (publishes buf[(t+1)&3] to all waves; also
//                                guarantees ring reuse safety for t+1's issue)
// Race-freedom: tile t's DMA targets buf[(t+3)&3] == buf[(t-1)&3]; every
// wave's LDS reads of that buffer completed before the end-of-(t-1) barrier
// (lgkmcnt waits precede the MFMAs that consume them), and tile t's body runs
// after that barrier. Publishing: end-of-t barrier follows every wave's
// vmcnt(8), which retires that wave's tile-(t+1) loads => buf[(t+1)&3] is
// fully written before any wave reads it in tile t+1.
// Ledger (4 loads/thread/tile): prologue 12 (tiles 0-2), vmcnt(8) -> tile 0
// ready. Tile t issues 4 -> outstanding {t+1,t+2,t+3}=12; vmcnt(8) retires
// t+1. Tail: vmcnt(4) then vmcnt(0).
// LDS swizzle: 64B rows, 4 chunks of 16B; chunk c of row r stored at
// c ^ ((r>>1)&3)  (involution; frag reads spread across all 8 bank-quads,
// 2-way = free).
// ---------------------------------------------------------------------------
template <int K, typename OutT>
__global__ __launch_bounds__(512, 2)
void gemm_bt_relu_8p(const unsigned short* __restrict__ A,
                     const unsigned short* __restrict__ Bt,
                     const float* __restrict__ bias,
                     OutT* __restrict__ C)
{
    constexpr int N  = 1024;
    constexpr int BK = 32;
    constexpr int NT = K / BK;

    __shared__ __align__(16) unsigned short As[4][256 * BK];  // 64 KB
    __shared__ __align__(16) unsigned short Bs[4][256 * BK];  // 64 KB

    const int tid  = threadIdx.x;
    const int wave = tid >> 6;
    const int lane = tid & 63;
    const int quad = lane >> 4;
    const int l16  = lane & 15;
    const int wm   = (wave >> 2) * 128;
    const int wn   = (wave & 3) * 64;

    // XCD-aware bijective swizzle: 256 blocks, 8 XCDs, 32 contiguous tiles
    // per XCD (4 bn-neighbors share an A-panel within one XCD's chunk).
    const int swz = (blockIdx.x & 7) * 32 + (blockIdx.x >> 3);
    const int bm  = (swz >> 2) * 256;
    const int bn  = (swz & 3) * 256;

    // staging map: slot s = j*512+tid -> row r = s>>2, stored pos p = s&3,
    // source chunk c = p ^ ((r>>1)&3)  (involution => read uses same XOR).
    const unsigned short* ag[2];
    const unsigned short* bg[2];
    int ao[2];
#pragma unroll
    for (int j = 0; j < 2; j++) {
        const int s = j * 512 + tid;
        const int r = s >> 2;
        const int c = (s & 3) ^ ((r >> 1) & 3);
        ag[j] = A  + (size_t)(bm + r) * K + c * 8;
        bg[j] = Bt + (size_t)(bn + r) * K + c * 8;
        ao[j] = s * 8;                       // element offset inside a buffer
    }

    // prologue: prefetch K-tiles 0..2
#pragma unroll
    for (int t = 0; t < 3; t++) {
#pragma unroll
        for (int j = 0; j < 2; j++) async_copy16(ag[j] + t * BK, &As[t][ao[j]]);
#pragma unroll
        for (int j = 0; j < 2; j++) async_copy16(bg[j] + t * BK, &Bs[t][ao[j]]);
    }
    asm volatile("s_waitcnt vmcnt(8)" ::: "memory");   // tile 0 landed
    __builtin_amdgcn_s_barrier();

    f32x4 acc[8][4] = {};

    for (int t = 0; t < NT; ++t) {
        const unsigned short* Ab = As[t & 3];
        const unsigned short* Bb = Bs[t & 3];

        // all 12 fragment reads for this tile
        bf16x8 bf[4], a0[4], a1[4];
#pragma unroll
        for (int i = 0; i < 4; i++) {
            const int row = wn + i * 16 + l16;
            bf[i] = *reinterpret_cast<const bf16x8*>(
                Bb + row * BK + ((quad ^ ((row >> 1) & 3)) << 3));
        }
#pragma unroll
        for (int i = 0; i < 4; i++) {
            const int row = wm + i * 16 + l16;
            a0[i] = *reinterpret_cast<const bf16x8*>(
                Ab + row * BK + ((quad ^ ((row >> 1) & 3)) << 3));
        }
#pragma unroll
        for (int i = 0; i < 4; i++) {
            const int row = wm + 64 + i * 16 + l16;
            a1[i] = *reinterpret_cast<const bf16x8*>(
                Ab + row * BK + ((quad ^ ((row >> 1) & 3)) << 3));
        }

        // issue tile t+3's staging (A and B) into the recycled ring slot
        if (t + 3 < NT) {
            const int tb = (t + 3) & 3;
            const int k0 = (t + 3) * BK;
#pragma unroll
            for (int j = 0; j < 2; j++) async_copy16(ag[j] + k0, &As[tb][ao[j]]);
#pragma unroll
            for (int j = 0; j < 2; j++) async_copy16(bg[j] + k0, &Bs[tb][ao[j]]);
        }

        // 32 MFMA under raised priority (compiler inserts lgkmcnt waits)
        __builtin_amdgcn_s_setprio(1);
#pragma unroll
        for (int mi = 0; mi < 4; mi++)
#pragma unroll
            for (int ni = 0; ni < 4; ni++)
                acc[mi][ni] = __builtin_amdgcn_mfma_f32_16x16x32_bf16(
                    a0[mi], bf[ni], acc[mi][ni], 0, 0, 0);
#pragma unroll
        for (int mi = 0; mi < 4; mi++)
#pragma unroll
            for (int ni = 0; ni < 4; ni++)
                acc[mi + 4][ni] = __builtin_amdgcn_mfma_f32_16x16x32_bf16(
                    a1[mi], bf[ni], acc[mi + 4][ni], 0, 0, 0);
        __builtin_amdgcn_s_setprio(0);

        // counted drain: retire exactly tile t+1's 4 loads, keep the rest
        if (t + 3 < NT)      asm volatile("s_waitcnt vmcnt(8)" ::: "memory");
        else if (t + 2 < NT) asm volatile("s_waitcnt vmcnt(4)" ::: "memory");
        else                 asm volatile("s_waitcnt vmcnt(0)" ::: "memory");
        __builtin_amdgcn_s_barrier();
    }

    // epilogue: bias + relu + store. C/D layout: row = quad*4 + r, col = l16
#pragma unroll
    for (int ni = 0; ni < 4; ni++) {
        const int n  = bn + wn + ni * 16 + l16;
        const float bv = bias[n];
#pragma unroll
        for (int mi = 0; mi < 8; mi++) {
            const int mbase = bm + wm + mi * 16 + quad * 4;
#pragma unroll
            for (int r = 0; r < 4; r++) {
                float v = fmaxf(acc[mi][ni][r] + bv, 0.0f);
                if constexpr (sizeof(OutT) == 2)
                    C[(size_t)(mbase + r) * N + n] = (OutT)f2b_rne(v);
                else
                    C[(size_t)(mbase + r) * N + n] = (OutT)v;
            }
        }
    }
}

// ---------------------------------------------------------------------------
// Launch
// ---------------------------------------------------------------------------
extern "C" void kernel_launch(void* const* d_in, const int* in_sizes, int n_in,
                              void* d_out, int out_size, void* d_ws, size_t ws_size,
                              hipStream_t stream)
{
    constexpr int N_ROUTES  = 16384;
    constexpr int N_NODES   = 100000;
    constexpr int D_GRAPH   = 512;
    constexpr int D_ROUTE   = 1024;
    constexpr int ROUTE_LEN = 32;

    const float* graph = (const float*)d_in[0];
    const int*   idx   = (const int*)d_in[1];
    const float* W0    = (const float*)d_in[2];
    const float* b0    = (const float*)d_in[3];
    const float* W1    = (const float*)d_in[4];
    const float* b1    = (const float*)d_in[5];
    const float* W2    = (const float*)d_in[6];
    const float* b2    = (const float*)d_in[7];
    float*       out   = (float*)d_out;

    // idx dtype from byte size (int64 => stride 64 ints, step 2)
    const bool is64   = (in_sizes[1] == N_ROUTES * ROUTE_LEN * 8);
    const int  stride = is64 ? 2 * ROUTE_LEN : ROUTE_LEN;
    const int  step   = is64 ? 2 : 1;

    // workspace carve
    char* w = (char*)d_ws;
    unsigned short* Wt0    = (unsigned short*)w; w += (size_t)D_ROUTE * D_GRAPH * 2;  // 1 MB
    unsigned short* Wt1    = (unsigned short*)w; w += (size_t)D_ROUTE * D_ROUTE * 2;  // 2 MB
    unsigned short* Wt2    = (unsigned short*)w; w += (size_t)D_ROUTE * D_ROUTE * 2;  // 2 MB
    unsigned short* routes = (unsigned short*)w; w += (size_t)N_ROUTES * D_GRAPH * 2; // 16 MB
    unsigned short* x1     = (unsigned short*)w; w += (size_t)N_ROUTES * D_ROUTE * 2; // 32 MB
    unsigned short* x2     = (unsigned short*)w; w += (size_t)N_ROUTES * D_ROUTE * 2; // 32 MB
    unsigned short* graphb = (unsigned short*)w;
    const size_t need_bf16 = (size_t)(w - (char*)d_ws) + (size_t)N_NODES * D_GRAPH * 2;
    const bool   use_bf16  = (ws_size >= need_bf16);

    constexpr int CONV_BLOCKS = (N_NODES * D_GRAPH / 8) / 256;   // 25000
    constexpr int TR_BLOCKS   = 512 + 1024 + 1024;               // 2560
    constexpr int GB          = N_ROUTES / 16;                   // 1024 gather blocks

    if (use_bf16) {
        // 1) graph cast to bf16
        convert_f32_bf16<<<CONV_BLOCKS, 256, 0, stream>>>(graph, graphb);
        // 2) gather+max, with the 3 weight transposes riding in its shadow
        gather_tr<<<GB + TR_BLOCKS, 256, 0, stream>>>(
            GB, stride, step, graphb, idx, routes, W0, Wt0, W1, Wt1, W2, Wt2);
    } else {
        // transposes only (gather_blocks = 0), then fp32 gather
        gather_tr<<<TR_BLOCKS, 256, 0, stream>>>(
            0, stride, step, nullptr, idx, routes, W0, Wt0, W1, Wt1, W2, Wt2);
        gather_max_f32<<<N_ROUTES / 8, 256, 0, stream>>>(stride, step, graph, idx, routes);
    }

    // 3) linear chain: 256x256-tile pipelined GEMMs (grid = 64x4 = 256 = #CUs)
    gemm_bt_relu_8p<512,  unsigned short><<<256, 512, 0, stream>>>(routes, Wt0, b0, x1);
    gemm_bt_relu_8p<1024, unsigned short><<<256, 512, 0, stream>>>(x1, Wt1, b1, x2);
    gemm_bt_relu_8p<1024, float><<<256, 512, 0, stream>>>(x2, Wt2, b2, out);
}

// Round 5
// 484.079 us; speedup vs baseline: 1.1229x; 1.0306x over previous
//
#include <hip/hip_runtime.h>
#include <hip/hip_bf16.h>
#include <cstdint>

// ---------------------------------------------------------------------------
// RoutesEncoder: gather+max over graph embedding, then 3x (Linear + ReLU).
// Established: fp32 inputs, fp32 output, bf16-space comparison (thr 1.578e-2),
// idx int32/int64 from in_sizes (host-side). Internals: bf16 MFMA, fp32 accum.
// R6: GEMM = 256x256 / 8-wave / ring-4 BK=32 deep pipeline, counted vmcnt.
// R7: gather idx staged in LDS; launches merged.
// R8: GEMM one barrier/K-tile; transposes ride the gather launch; is64 on host.
// R9/R10: cache-residency round. (a) convert reads the fp32 graph with
//     NON-TEMPORAL loads (via ext-vector f32x4 -- HIP float4 struct is
//     rejected by the builtin): fp32 lines are dead after the cast;
//     deprioritizing them keeps the 102 MB bf16 table L3-resident for the
//     gather (205+102 MB > 256 MB L3 otherwise evicts part of it).
//     (b) GEMM3's fp32 output (64 MB, never re-read) stored non-temporal.
//     No numeric changes.
// ---------------------------------------------------------------------------

typedef __attribute__((ext_vector_type(8))) short          bf16x8; // MFMA A/B frag
typedef __attribute__((ext_vector_type(8))) unsigned short u16x8;  // 16B vector ld/st
typedef __attribute__((ext_vector_type(4))) float          f32x4;  // MFMA C/D frag + NT loads

__device__ __forceinline__ unsigned short f2b_rne(float f) {
    union { float f; uint32_t i; } x; x.f = f;
    uint32_t lsb = (x.i >> 16) & 1u;
    return (unsigned short)((x.i + 0x7fffu + lsb) >> 16);
}
__device__ __forceinline__ float b2f(unsigned short u) {
    union { float f; uint32_t i; } x; x.i = ((uint32_t)u) << 16; return x.f;
}

// async 16B global->LDS DMA. HW scatters lane i to ldsbase + i*16; our lptr is
// exactly base + lane*16 in wave-lane order (contract verified round 4).
__device__ __forceinline__ void async_copy16(const void* gptr, void* lptr) {
    __builtin_amdgcn_global_load_lds(
        (const __attribute__((address_space(1))) unsigned int*)gptr,
        (__attribute__((address_space(3))) unsigned int*)lptr, 16, 0, 0);
}

// ---------------------------------------------------------------------------
// Streaming cast: graph fp32 -> bf16 (RNE). 8 floats/thread. Exact for the
// downstream max since RNE is monotone => max(rne(x)) == rne(max(x)).
// Non-temporal reads: fp32 lines are dead after this kernel; keep them from
// evicting the bf16 table (which gather needs L3-resident) from L3.
// ---------------------------------------------------------------------------
__global__ __launch_bounds__(256)
void convert_f32_bf16(const float* __restrict__ in, unsigned short* __restrict__ out)
{
    const size_t i = ((size_t)blockIdx.x * 256 + threadIdx.x) * 8;
    const f32x4* p = reinterpret_cast<const f32x4*>(in + i);
    f32x4 v0 = __builtin_nontemporal_load(p);
    f32x4 v1 = __builtin_nontemporal_load(p + 1);
    u16x8 o;
    o[0] = f2b_rne(v0[0]); o[1] = f2b_rne(v0[1]); o[2] = f2b_rne(v0[2]); o[3] = f2b_rne(v0[3]);
    o[4] = f2b_rne(v1[0]); o[5] = f2b_rne(v1[1]); o[6] = f2b_rne(v1[2]); o[7] = f2b_rne(v1[3]);
    *reinterpret_cast<u16x8*>(out + i) = o;
}

// ---------------------------------------------------------------------------
// Gather+max (blocks [0, gather_blocks)) + weight transpose-casts (rest).
// Gather: one wave = 4 routes, row = 1KB = 64 lanes x 16B; block's 16x32
// indices staged in LDS first so the idx load leaves the dependent chain;
// unroll 4 => 16 independent row-loads in flight per wave.
// Transpose: fp32 W[K,1024] -> bf16 Wt[1024,K], 32x32 tiles; rides in the
// same launch to hide under the gather's latency-bound execution.
// ---------------------------------------------------------------------------
__global__ __launch_bounds__(256)
void gather_tr(int gather_blocks, int stride, int step,
               const unsigned short* __restrict__ graphb,
               const int* __restrict__ idx32,
               unsigned short* __restrict__ routes,
               const float* __restrict__ W0, unsigned short* __restrict__ Wt0,
               const float* __restrict__ W1, unsigned short* __restrict__ Wt1,
               const float* __restrict__ W2, unsigned short* __restrict__ Wt2)
{
    __shared__ int   sidx[16][32];
    __shared__ float tile[32][33];

    if ((int)blockIdx.x < gather_blocks) {
        const int route0 = blockIdx.x * 16;
        // cooperative idx stage: 512 entries, 2 per thread
        for (int e = threadIdx.x; e < 512; e += 256) {
            const int r = e >> 5, l = e & 31;
            sidx[r][l] = idx32[(size_t)(route0 + r) * stride + l * step];
        }
        __syncthreads();

        const int wave = threadIdx.x >> 6;
        const int lane = threadIdx.x & 63;
        const int rl   = wave * 4;                  // local route base
        const int col  = lane * 8;                  // 8 bf16 = 16B per lane

        float m[4][8];
#pragma unroll
        for (int t = 0; t < 4; t++)
#pragma unroll
            for (int j = 0; j < 8; j++) m[t][j] = -INFINITY;

#pragma unroll 4
        for (int l = 0; l < 32; l++) {
            u16x8 v[4];
#pragma unroll
            for (int t = 0; t < 4; t++) {
                const int node = sidx[rl + t][l];   // LDS broadcast
                v[t] = *reinterpret_cast<const u16x8*>(graphb + (size_t)node * 512 + col);
            }
#pragma unroll
            for (int t = 0; t < 4; t++)
#pragma unroll
                for (int j = 0; j < 8; j++)
                    m[t][j] = fmaxf(m[t][j], b2f(v[t][j]));
        }
#pragma unroll
        for (int t = 0; t < 4; t++) {
            u16x8 o;
#pragma unroll
            for (int j = 0; j < 8; j++) {
                union { float f; uint32_t i; } x; x.f = m[t][j];
                o[j] = (unsigned short)(x.i >> 16);   // exact: max of bf16s is a bf16
            }
            *reinterpret_cast<u16x8*>(routes + (size_t)(route0 + rl + t) * 512 + col) = o;
        }
        return;
    }

    // ---- transpose-cast region: W0 (K=512): 512 blocks; W1,W2: 1024 each
    int b = blockIdx.x - gather_blocks;
    const float* W; unsigned short* Wt; int K;
    if (b < 512)       { W = W0; Wt = Wt0; K = 512;  }
    else if (b < 1536) { b -= 512;  W = W1; Wt = Wt1; K = 1024; }
    else               { b -= 1536; W = W2; Wt = Wt2; K = 1024; }
    constexpr int N = 1024;
    const int n0 = (b & 31) * 32;        // N/32 = 32 tiles across
    const int k0 = (b >> 5) * 32;
    const int tx = threadIdx.x & 31;
    const int ty = threadIdx.x >> 5;
#pragma unroll
    for (int i = 0; i < 32; i += 8)
        tile[ty + i][tx] = W[(size_t)(k0 + ty + i) * N + (n0 + tx)];
    __syncthreads();
#pragma unroll
    for (int i = 0; i < 32; i += 8)
        Wt[(size_t)(n0 + ty + i) * K + (k0 + tx)] = f2b_rne(tile[tx][ty + i]);
}

// fp32-table fallback (2 routes/wave) if ws can't hold graphb
__global__ void gather_max_f32(int stride, int step,
                               const float* __restrict__ graph,
                               const int* __restrict__ idx32,
                               unsigned short* __restrict__ routes)
{
    const int wave  = threadIdx.x >> 6;
    const int lane  = threadIdx.x & 63;
    const int route = (blockIdx.x * 4 + wave) * 2;
    const int col   = lane * 8;

    float m0[8], m1[8];
#pragma unroll
    for (int j = 0; j < 8; j++) { m0[j] = -INFINITY; m1[j] = -INFINITY; }

    const int* ip0 = idx32 + (size_t)route * stride;
    const int* ip1 = ip0 + stride;
#pragma unroll 4
    for (int l = 0; l < 32; l++) {
        const int n0 = ip0[l * step];
        const int n1 = ip1[l * step];
        const float4* p0 = reinterpret_cast<const float4*>(graph + (size_t)n0 * 512 + col);
        const float4* p1 = reinterpret_cast<const float4*>(graph + (size_t)n1 * 512 + col);
        float4 a0 = p0[0], a1 = p0[1];
        float4 b0 = p1[0], b1 = p1[1];
        m0[0] = fmaxf(m0[0], a0.x); m0[1] = fmaxf(m0[1], a0.y);
        m0[2] = fmaxf(m0[2], a0.z); m0[3] = fmaxf(m0[3], a0.w);
        m0[4] = fmaxf(m0[4], a1.x); m0[5] = fmaxf(m0[5], a1.y);
        m0[6] = fmaxf(m0[6], a1.z); m0[7] = fmaxf(m0[7], a1.w);
        m1[0] = fmaxf(m1[0], b0.x); m1[1] = fmaxf(m1[1], b0.y);
        m1[2] = fmaxf(m1[2], b0.z); m1[3] = fmaxf(m1[3], b0.w);
        m1[4] = fmaxf(m1[4], b1.x); m1[5] = fmaxf(m1[5], b1.y);
        m1[6] = fmaxf(m1[6], b1.z); m1[7] = fmaxf(m1[7], b1.w);
    }
    u16x8 o0, o1;
#pragma unroll
    for (int j = 0; j < 8; j++) { o0[j] = f2b_rne(m0[j]); o1[j] = f2b_rne(m1[j]); }
    *reinterpret_cast<u16x8*>(routes + (size_t)route * 512 + col)       = o0;
    *reinterpret_cast<u16x8*>(routes + (size_t)(route + 1) * 512 + col) = o1;
}

// ---------------------------------------------------------------------------
// GEMM (B^T): C = relu(A[M,K]*Bt[N,K]^T + bias). bf16 in, fp32 accum.
// 256x256 tile, 8 waves (2M x 4N), 128x64 per wave, acc[8][4] 16x16x32 MFMA.
// BK=32 K-tiles in a ring of 4 LDS buffers (128 KiB), prefetch distance 3.
// ONE barrier per tile. Per tile t:
//   12 ds_read_b128 (A 8 + B 4, from buf[t&3])
//   issue 4 global_load_lds for tile t+3 into buf[(t+3)&3]
//   setprio(1); 32 MFMA; setprio(0)
//   counted s_waitcnt vmcnt(8)  (retires exactly tile t+1's 4 loads)
//   s_barrier                   (publishes buf[(t+1)&3]; protects ring reuse)
// Ledger (4 loads/thread/tile): prologue 12 (tiles 0-2), vmcnt(8) -> tile 0
// ready. Tile t issues 4 -> outstanding {t+1,t+2,t+3}=12; vmcnt(8) retires
// t+1. Tail: vmcnt(4) then vmcnt(0).
// LDS swizzle: 64B rows, 4 chunks of 16B; chunk c of row r stored at
// c ^ ((r>>1)&3) (involution; frag reads spread across all 8 bank-quads).
// fp32 output (GEMM3, never re-read by us) stored non-temporal.
// ---------------------------------------------------------------------------
template <int K, typename OutT>
__global__ __launch_bounds__(512, 2)
void gemm_bt_relu_8p(const unsigned short* __restrict__ A,
                     const unsigned short* __restrict__ Bt,
                     const float* __restrict__ bias,
                     OutT* __restrict__ C)
{
    constexpr int N  = 1024;
    constexpr int BK = 32;
    constexpr int NT = K / BK;

    __shared__ __align__(16) unsigned short As[4][256 * BK];  // 64 KB
    __shared__ __align__(16) unsigned short Bs[4][256 * BK];  // 64 KB

    const int tid  = threadIdx.x;
    const int wave = tid >> 6;
    const int lane = tid & 63;
    const int quad = lane >> 4;
    const int l16  = lane & 15;
    const int wm   = (wave >> 2) * 128;
    const int wn   = (wave & 3) * 64;

    // XCD-aware bijective swizzle: 256 blocks, 8 XCDs, 32 contiguous tiles
    // per XCD (4 bn-neighbors share an A-panel within one XCD's chunk).
    const int swz = (blockIdx.x & 7) * 32 + (blockIdx.x >> 3);
    const int bm  = (swz >> 2) * 256;
    const int bn  = (swz & 3) * 256;

    // staging map: slot s = j*512+tid -> row r = s>>2, stored pos p = s&3,
    // source chunk c = p ^ ((r>>1)&3)  (involution => read uses same XOR).
    const unsigned short* ag[2];
    const unsigned short* bg[2];
    int ao[2];
#pragma unroll
    for (int j = 0; j < 2; j++) {
        const int s = j * 512 + tid;
        const int r = s >> 2;
        const int c = (s & 3) ^ ((r >> 1) & 3);
        ag[j] = A  + (size_t)(bm + r) * K + c * 8;
        bg[j] = Bt + (size_t)(bn + r) * K + c * 8;
        ao[j] = s * 8;                       // element offset inside a buffer
    }

    // prologue: prefetch K-tiles 0..2
#pragma unroll
    for (int t = 0; t < 3; t++) {
#pragma unroll
        for (int j = 0; j < 2; j++) async_copy16(ag[j] + t * BK, &As[t][ao[j]]);
#pragma unroll
        for (int j = 0; j < 2; j++) async_copy16(bg[j] + t * BK, &Bs[t][ao[j]]);
    }
    asm volatile("s_waitcnt vmcnt(8)" ::: "memory");   // tile 0 landed
    __builtin_amdgcn_s_barrier();

    f32x4 acc[8][4] = {};

    for (int t = 0; t < NT; ++t) {
        const unsigned short* Ab = As[t & 3];
        const unsigned short* Bb = Bs[t & 3];

        // all 12 fragment reads for this tile
        bf16x8 bf[4], a0[4], a1[4];
#pragma unroll
        for (int i = 0; i < 4; i++) {
            const int row = wn + i * 16 + l16;
            bf[i] = *reinterpret_cast<const bf16x8*>(
                Bb + row * BK + ((quad ^ ((row >> 1) & 3)) << 3));
        }
#pragma unroll
        for (int i = 0; i < 4; i++) {
            const int row = wm + i * 16 + l16;
            a0[i] = *reinterpret_cast<const bf16x8*>(
                Ab + row * BK + ((quad ^ ((row >> 1) & 3)) << 3));
        }
#pragma unroll
        for (int i = 0; i < 4; i++) {
            const int row = wm + 64 + i * 16 + l16;
            a1[i] = *reinterpret_cast<const bf16x8*>(
                Ab + row * BK + ((quad ^ ((row >> 1) & 3)) << 3));
        }

        // issue tile t+3's staging (A and B) into the recycled ring slot
        if (t + 3 < NT) {
            const int tb = (t + 3) & 3;
            const int k0 = (t + 3) * BK;
#pragma unroll
            for (int j = 0; j < 2; j++) async_copy16(ag[j] + k0, &As[tb][ao[j]]);
#pragma unroll
            for (int j = 0; j < 2; j++) async_copy16(bg[j] + k0, &Bs[tb][ao[j]]);
        }

        // 32 MFMA under raised priority (compiler inserts lgkmcnt waits)
        __builtin_amdgcn_s_setprio(1);
#pragma unroll
        for (int mi = 0; mi < 4; mi++)
#pragma unroll
            for (int ni = 0; ni < 4; ni++)
                acc[mi][ni] = __builtin_amdgcn_mfma_f32_16x16x32_bf16(
                    a0[mi], bf[ni], acc[mi][ni], 0, 0, 0);
#pragma unroll
        for (int mi = 0; mi < 4; mi++)
#pragma unroll
            for (int ni = 0; ni < 4; ni++)
                acc[mi + 4][ni] = __builtin_amdgcn_mfma_f32_16x16x32_bf16(
                    a1[mi], bf[ni], acc[mi + 4][ni], 0, 0, 0);
        __builtin_amdgcn_s_setprio(0);

        // counted drain: retire exactly tile t+1's 4 loads, keep the rest
        if (t + 3 < NT)      asm volatile("s_waitcnt vmcnt(8)" ::: "memory");
        else if (t + 2 < NT) asm volatile("s_waitcnt vmcnt(4)" ::: "memory");
        else                 asm volatile("s_waitcnt vmcnt(0)" ::: "memory");
        __builtin_amdgcn_s_barrier();
    }

    // epilogue: bias + relu + store. C/D layout: row = quad*4 + r, col = l16
#pragma unroll
    for (int ni = 0; ni < 4; ni++) {
        const int n  = bn + wn + ni * 16 + l16;
        const float bv = bias[n];
#pragma unroll
        for (int mi = 0; mi < 8; mi++) {
            const int mbase = bm + wm + mi * 16 + quad * 4;
#pragma unroll
            for (int r = 0; r < 4; r++) {
                float v = fmaxf(acc[mi][ni][r] + bv, 0.0f);
                if constexpr (sizeof(OutT) == 2) {
                    C[(size_t)(mbase + r) * N + n] = (OutT)f2b_rne(v);
                } else {
                    // final fp32 output: never re-read by us -> non-temporal
                    __builtin_nontemporal_store(v, &C[(size_t)(mbase + r) * N + n]);
                }
            }
        }
    }
}

// ---------------------------------------------------------------------------
// Launch
// ---------------------------------------------------------------------------
extern "C" void kernel_launch(void* const* d_in, const int* in_sizes, int n_in,
                              void* d_out, int out_size, void* d_ws, size_t ws_size,
                              hipStream_t stream)
{
    constexpr int N_ROUTES  = 16384;
    constexpr int N_NODES   = 100000;
    constexpr int D_GRAPH   = 512;
    constexpr int D_ROUTE   = 1024;
    constexpr int ROUTE_LEN = 32;

    const float* graph = (const float*)d_in[0];
    const int*   idx   = (const int*)d_in[1];
    const float* W0    = (const float*)d_in[2];
    const float* b0    = (const float*)d_in[3];
    const float* W1    = (const float*)d_in[4];
    const float* b1    = (const float*)d_in[5];
    const float* W2    = (const float*)d_in[6];
    const float* b2    = (const float*)d_in[7];
    float*       out   = (float*)d_out;

    // idx dtype from byte size (int64 => stride 64 ints, step 2)
    const bool is64   = (in_sizes[1] == N_ROUTES * ROUTE_LEN * 8);
    const int  stride = is64 ? 2 * ROUTE_LEN : ROUTE_LEN;
    const int  step   = is64 ? 2 : 1;

    // workspace carve
    char* w = (char*)d_ws;
    unsigned short* Wt0    = (unsigned short*)w; w += (size_t)D_ROUTE * D_GRAPH * 2;  // 1 MB
    unsigned short* Wt1    = (unsigned short*)w; w += (size_t)D_ROUTE * D_ROUTE * 2;  // 2 MB
    unsigned short* Wt2    = (unsigned short*)w; w += (size_t)D_ROUTE * D_ROUTE * 2;  // 2 MB
    unsigned short* routes = (unsigned short*)w; w += (size_t)N_ROUTES * D_GRAPH * 2; // 16 MB
    unsigned short* x1     = (unsigned short*)w; w += (size_t)N_ROUTES * D_ROUTE * 2; // 32 MB
    unsigned short* x2     = (unsigned short*)w; w += (size_t)N_ROUTES * D_ROUTE * 2; // 32 MB
    unsigned short* graphb = (unsigned short*)w;
    const size_t need_bf16 = (size_t)(w - (char*)d_ws) + (size_t)N_NODES * D_GRAPH * 2;
    const bool   use_bf16  = (ws_size >= need_bf16);

    constexpr int CONV_BLOCKS = (N_NODES * D_GRAPH / 8) / 256;   // 25000
    constexpr int TR_BLOCKS   = 512 + 1024 + 1024;               // 2560
    constexpr int GB          = N_ROUTES / 16;                   // 1024 gather blocks

    if (use_bf16) {
        // 1) graph cast to bf16 (NT reads keep graphb L3-resident for gather)
        convert_f32_bf16<<<CONV_BLOCKS, 256, 0, stream>>>(graph, graphb);
        // 2) gather+max, with the 3 weight transposes riding in its shadow
        gather_tr<<<GB + TR_BLOCKS, 256, 0, stream>>>(
            GB, stride, step, graphb, idx, routes, W0, Wt0, W1, Wt1, W2, Wt2);
    } else {
        // transposes only (gather_blocks = 0), then fp32 gather
        gather_tr<<<TR_BLOCKS, 256, 0, stream>>>(
            0, stride, step, nullptr, idx, routes, W0, Wt0, W1, Wt1, W2, Wt2);
        gather_max_f32<<<N_ROUTES / 8, 256, 0, stream>>>(stride, step, graph, idx, routes);
    }

    // 3) linear chain: 256x256-tile pipelined GEMMs (grid = 64x4 = 256 = #CUs)
    gemm_bt_relu_8p<512,  unsigned short><<<256, 512, 0, stream>>>(routes, Wt0, b0, x1);
    gemm_bt_relu_8p<1024, unsigned short><<<256, 512, 0, stream>>>(x1, Wt1, b1, x2);
    gemm_bt_relu_8p<1024, float><<<256, 512, 0, stream>>>(x2, Wt2, b2, out);
}